// Round 5
// baseline (1160.449 us; speedup 1.0000x reference)
//
#include <hip/hip_runtime.h>

#define N_NODES 50000
#define N_EDGES 1600000
#define HID     128
#define N_GRAPHS 64

#define HIST_BLOCKS 128
#define EPB (N_EDGES / HIST_BLOCKS)      // 12500 edges per block
#define NWORDS 25000                     // 50000 nodes packed 2-per-u32
#define FILL_PASSES 4
#define NPP 12500                        // nodes per fill pass
#define WPP (NPP / 2)                    // 6250 cursor words per pass

// workspace layout (4-byte words) — 8.15M words = 32.6 MB
#define WS_DEG   0u         // int[50000]
#define WS_BSUM  50000u     // int[256]
#define WS_BOFF  50256u     // int[256]
#define WS_OFFS  50512u     // int[50000]
#define WS_INVD  100512u    // float[50000]
#define WS_CSR   150512u    // int[1600000]
#define WS_HIST  1750512u   // uint[3200000] = hist[128][25000]; dead after fill -> aliased as agg16
#define WS_XB16  4950512u   // uint[3200000] (bf16 x2: 50000x128)
#define WS_END   8150512u

// ---- bf16 helpers (raw, RN-even pack; fp32 math everywhere) ----
__device__ __forceinline__ float bf_lo(unsigned u) { return __uint_as_float(u << 16); }
__device__ __forceinline__ float bf_hi(unsigned u) { return __uint_as_float(u & 0xffff0000u); }
__device__ __forceinline__ unsigned bf_rn(float f) {
    unsigned u = __float_as_uint(f);
    unsigned r = ((u >> 16) & 1u) + 0x7fffu;
    return (u + r) >> 16;
}
__device__ __forceinline__ unsigned bf_pack(float lo, float hi) {
    return bf_rn(lo) | (bf_rn(hi) << 16);
}

// ---------------- x0 fp32 -> bf16 ----------------
__global__ __launch_bounds__(256) void k_cvt(const float4* __restrict__ x, uint2* __restrict__ o) {
    int i = blockIdx.x * 256 + threadIdx.x;      // 1.6M total
    float4 v = x[i];
    uint2 r;
    r.x = bf_pack(v.x, v.y);
    r.y = bf_pack(v.z, v.w);
    o[i] = r;
}

// ---------------- CSR build: atomic-free (LDS histograms + block-partial scan) ----------------

// Stage 1: per-block LDS histogram of dst over its edge slice. Packed u16x2.
__global__ __launch_bounds__(256) void k_hist(const int* __restrict__ ei, unsigned* __restrict__ hist) {
    __shared__ unsigned sh[NWORDS];
    for (int i = threadIdx.x; i < NWORDS; i += 256) sh[i] = 0;
    __syncthreads();
    const int e0 = blockIdx.x * EPB;
    for (int i = threadIdx.x; i < EPB; i += 256) {
        int d = __builtin_nontemporal_load(ei + N_EDGES + e0 + i);
        atomicAdd(&sh[d >> 1], 1u << ((d & 1) << 4));
    }
    __syncthreads();
    unsigned* hb = hist + (size_t)blockIdx.x * NWORDS;
    for (int i = threadIdx.x; i < NWORDS; i += 256) hb[i] = sh[i];
}

// Stage 2: exclusive scan over the 128 block-partials per node (packed u16 scan).
__global__ __launch_bounds__(256) void k_scanb(unsigned* __restrict__ hist, int* __restrict__ deg) {
    int w = blockIdx.x * 256 + threadIdx.x;
    if (w >= NWORDS) return;
    unsigned run = 0;
#pragma unroll 8
    for (int b = 0; b < HIST_BLOCKS; ++b) {
        unsigned u = hist[(size_t)b * NWORDS + w];
        hist[(size_t)b * NWORDS + w] = run;
        run += u;
    }
    deg[2 * w] = (int)(run & 0xffffu);
    deg[2 * w + 1] = (int)(run >> 16);
}

__global__ __launch_bounds__(256) void k_blockreduce(const int* __restrict__ deg, int* __restrict__ bsum) {
    __shared__ int s[256];
    int i = blockIdx.x * 256 + threadIdx.x;
    s[threadIdx.x] = (i < N_NODES) ? deg[i] : 0;
    __syncthreads();
    for (int d = 128; d > 0; d >>= 1) {
        if (threadIdx.x < d) s[threadIdx.x] += s[threadIdx.x + d];
        __syncthreads();
    }
    if (threadIdx.x == 0) bsum[blockIdx.x] = s[0];
}

__global__ __launch_bounds__(256) void k_scanblocks(const int* __restrict__ bsum, int* __restrict__ boff, int nb) {
    __shared__ int s[256];
    int t = threadIdx.x;
    int v = (t < nb) ? bsum[t] : 0;
    s[t] = v;
    __syncthreads();
    for (int d = 1; d < 256; d <<= 1) {
        int add = (t >= d) ? s[t - d] : 0;
        __syncthreads();
        s[t] += add;
        __syncthreads();
    }
    if (t < nb) boff[t] = s[t] - v;   // exclusive
}

__global__ __launch_bounds__(256) void k_offsets(const int* __restrict__ deg, const int* __restrict__ boff,
                                                 int* __restrict__ offs, float* __restrict__ invdeg) {
    __shared__ int s[256];
    int b = blockIdx.x, t = threadIdx.x;
    int i = b * 256 + t;
    int v = (i < N_NODES) ? deg[i] : 0;
    s[t] = v;
    __syncthreads();
    for (int d = 1; d < 256; d <<= 1) {
        int add = (t >= d) ? s[t - d] : 0;
        __syncthreads();
        s[t] += add;
        __syncthreads();
    }
    if (i < N_NODES) {
        offs[i] = boff[b] + s[t] - v;   // exclusive global offset
        invdeg[i] = 1.0f / fmaxf((float)v, 1.0f);
    }
}

// Stage 3: fill — ALL 4 node-range passes concurrent in one 512-block dispatch.
// s8 = blockIdx&7 rides XCD round-robin: each csr quarter written by <=2 XCDs
// (bounded partial-line write-amp). LDS atomics only. csr stores PRE-SCALED
// src word-offsets (src*64) so the gather kernel skips the per-edge multiply.
__global__ __launch_bounds__(256) void k_fill2(const int* __restrict__ ei, const int* __restrict__ offs,
                                               const unsigned* __restrict__ hist, int* __restrict__ csr) {
    __shared__ unsigned scur[WPP];   // 25 KB
    const int s8 = blockIdx.x & 7;
    const int pass = s8 >> 1;                              // 0..3 (XCD pair {2p,2p+1})
    const int b = ((blockIdx.x >> 3) << 1) | (s8 & 1);     // 0..127 edge slice
    const int nbase = pass * NPP;
    const unsigned* hb = hist + (size_t)b * NWORDS + pass * WPP;
    for (int i = threadIdx.x; i < WPP; i += 256) scur[i] = hb[i];
    __syncthreads();
    const int e0 = b * EPB;
    for (int i = threadIdx.x; i < EPB; i += 256) {
        int d = __builtin_nontemporal_load(ei + N_EDGES + e0 + i);
        unsigned rd = (unsigned)(d - nbase);
        if (rd < (unsigned)NPP) {
            int s = ei[e0 + i];
            int sh = (rd & 1) << 4;
            unsigned old = atomicAdd(&scur[rd >> 1], 1u << sh);
            unsigned rel = (old >> sh) & 0xffffu;
            csr[offs[d] + (int)rel] = s * 64;   // pre-scaled row word-offset
        }
    }
}

// ---------------- per-layer: XCD-sliced aggregation ----------------
// 8 column slices of 16 cols (32 B bf16); slice = blockIdx&7 == XCD under
// round-robin dispatch -> each XCD gathers from a 1.6 MB L2-resident x-slice.
// Wave: 8 edge slots x 8 words; butterfly-reduce over slots; csr via nt loads.

__global__ __launch_bounds__(256) void k_aggx(const unsigned* __restrict__ xb, const int* __restrict__ csr,
                                              const int* __restrict__ offs, const int* __restrict__ deg,
                                              const float* __restrict__ invdeg, unsigned* __restrict__ agg) {
    const int slice = blockIdx.x & 7;
    const int grp = blockIdx.x >> 3;           // 0..12499
    const int node = grp * 4 + (threadIdx.x >> 6);
    const int lane = threadIdx.x & 63;
    const int sub = lane >> 3;                 // edge slot 0..7
    const int word = lane & 7;                 // u32 word within slice
    const int beg = offs[node];
    const int dn = deg[node];
    const unsigned* xs = xb + (slice << 3) + word;
    float a0 = 0.f, a1 = 0.f;
    int j = sub;
    for (; j + 16 < dn; j += 16) {             // 2x unroll for MLP
        int s0 = __builtin_nontemporal_load(csr + beg + j);
        int s1 = __builtin_nontemporal_load(csr + beg + j + 8);
        unsigned u0 = xs[s0];
        unsigned u1 = xs[s1];
        a0 += bf_lo(u0) + bf_lo(u1);
        a1 += bf_hi(u0) + bf_hi(u1);
    }
    for (; j < dn; j += 8) {
        int s0 = __builtin_nontemporal_load(csr + beg + j);
        unsigned u0 = xs[s0];
        a0 += bf_lo(u0);
        a1 += bf_hi(u0);
    }
#pragma unroll
    for (int m = 8; m < 64; m <<= 1) {
        a0 += __shfl_xor(a0, m);
        a1 += __shfl_xor(a1, m);
    }
    if (sub == 0) {
        float id = invdeg[node];
        agg[(size_t)node * 64 + (slice << 3) + word] = bf_pack(a0 * id, a1 * id);
    }
}

// ---------------- per-layer: fused (agg@Wn + x@Wr + bn) -> LN -> ReLU ----------------

__global__ __launch_bounds__(256) void k_gemm_ln(
        const unsigned short* __restrict__ aggb, const unsigned short* __restrict__ xinb,
        const float* __restrict__ Wn, const float* __restrict__ Wr,
        const float* __restrict__ bn, const float* __restrict__ gam,
        const float* __restrict__ bet, float* __restrict__ xout,
        unsigned* __restrict__ b16out) {
    __shared__ float smem[32 * 36 + 32 * 128];   // 5248 floats = 21 KB
    float* A_lds = smem;            // [k][r] stride 36
    float* W_lds = smem + 32 * 36;  // [k][c] stride 128
    float* H = smem;                // [r][c] stride 132, aliases (4224 <= 5248)

    const int t = threadIdx.x;
    const int tx = t & 31;   // col group: cols tx*4 .. tx*4+3
    const int ty = t >> 5;   // row group: rows ty*4 .. ty*4+3
    const int row0 = blockIdx.x * 32;

    float acc[4][4];
#pragma unroll
    for (int i = 0; i < 4; i++)
#pragma unroll
        for (int j = 0; j < 4; j++) acc[i][j] = 0.f;

    for (int pass = 0; pass < 2; ++pass) {
        const unsigned short* A = pass ? xinb : aggb;
        const float* W = pass ? Wr : Wn;
        for (int k0 = 0; k0 < HID; k0 += 32) {
            __syncthreads();
            {   // stage A transposed (bf16 -> fp32): kk = t&31, rbase = t>>5 (+i*8)
                int kk = t & 31;
                int rb = t >> 5;
#pragma unroll
                for (int i = 0; i < 4; i++) {
                    int r = rb + i * 8;
                    int gr = row0 + r;
                    unsigned short raw = (gr < N_NODES) ? A[(size_t)gr * HID + k0 + kk] : (unsigned short)0;
                    A_lds[kk * 36 + r] = __uint_as_float(((unsigned)raw) << 16);
                }
            }
            {   // stage W: 32x128 = 4096 elems, 16 per thread, coalesced
#pragma unroll
                for (int i = 0; i < 16; i++) {
                    int idx = t + i * 256;
                    int kk = idx >> 7;
                    int c = idx & 127;
                    W_lds[idx] = W[(size_t)(k0 + kk) * HID + c];
                }
            }
            __syncthreads();
#pragma unroll
            for (int k = 0; k < 32; k++) {
                float4 a4 = *(const float4*)&A_lds[k * 36 + ty * 4];
                float4 w4 = *(const float4*)&W_lds[(k << 7) + tx * 4];
                float av[4] = {a4.x, a4.y, a4.z, a4.w};
                float wv[4] = {w4.x, w4.y, w4.z, w4.w};
#pragma unroll
                for (int i = 0; i < 4; i++)
#pragma unroll
                    for (int j = 0; j < 4; j++) acc[i][j] = fmaf(av[i], wv[j], acc[i][j]);
            }
        }
    }

    // epilogue: bias -> H (LDS) -> LayerNorm -> ReLU -> store fp32 + bf16
    __syncthreads();
    float4 b4 = *(const float4*)&bn[tx * 4];
#pragma unroll
    for (int i = 0; i < 4; i++) {
        float4 h4;
        h4.x = acc[i][0] + b4.x;
        h4.y = acc[i][1] + b4.y;
        h4.z = acc[i][2] + b4.z;
        h4.w = acc[i][3] + b4.w;
        *(float4*)&H[(ty * 4 + i) * 132 + tx * 4] = h4;
    }
    __syncthreads();

    int row = t >> 3;    // 0..31
    int sub = t & 7;     // 8 threads per row, 16 cols each
    const float* hr = &H[row * 132 + sub * 16];
    float v[16];
    float s = 0.f, s2 = 0.f;
#pragma unroll
    for (int i = 0; i < 16; i++) {
        v[i] = hr[i];
        s += v[i];
        s2 += v[i] * v[i];
    }
#pragma unroll
    for (int m = 1; m < 8; m <<= 1) {
        s += __shfl_xor(s, m);
        s2 += __shfl_xor(s2, m);
    }
    float mean = s * (1.f / 128.f);
    float var = s2 * (1.f / 128.f) - mean * mean;
    float rstd = rsqrtf(var + 1e-5f);
    int gr = row0 + row;
    if (gr < N_NODES) {
        int cb = sub * 16;
        float o[16];
#pragma unroll
        for (int i = 0; i < 16; i++) {
            int c = cb + i;
            o[i] = fmaxf((v[i] - mean) * rstd * gam[c] + bet[c], 0.f);
            xout[(size_t)gr * HID + c] = o[i];
        }
#pragma unroll
        for (int i = 0; i < 16; i += 2)
            b16out[(size_t)gr * 64 + ((cb + i) >> 1)] = bf_pack(o[i], o[i + 1]);
    }
}

// ---------------- graph mean-pool: atomic-free segmented reduction (bf16 input) ----------------

__global__ __launch_bounds__(256) void k_pool_seg(const unsigned* __restrict__ xb,
                                                  const int* __restrict__ batch,
                                                  float* __restrict__ out) {
    const int g = blockIdx.x;          // 0..63
    __shared__ int s_beg, s_end;
    if (threadIdx.x == 0) {
        int lo = 0, hi = N_NODES;
        while (lo < hi) { int mid = (lo + hi) >> 1; if (batch[mid] < g) lo = mid + 1; else hi = mid; }
        s_beg = lo;
        lo = 0; hi = N_NODES;
        while (lo < hi) { int mid = (lo + hi) >> 1; if (batch[mid] < g + 1) lo = mid + 1; else hi = mid; }
        s_end = lo;
    }
    __syncthreads();
    const int beg = s_beg, end = s_end;
    const int w = threadIdx.x & 63;    // u32 word (2 cols)
    const int q = threadIdx.x >> 6;    // row group 0..3
    float ax = 0.f, ay = 0.f;
    for (int r = beg + q; r < end; r += 4) {
        unsigned u = xb[(size_t)r * 64 + w];
        ax += bf_lo(u);
        ay += bf_hi(u);
    }
    __shared__ float sx[4][64], sy[4][64];
    sx[q][w] = ax;
    sy[q][w] = ay;
    __syncthreads();
    if (q == 0) {
        float tx = sx[0][w] + sx[1][w] + sx[2][w] + sx[3][w];
        float ty = sy[0][w] + sy[1][w] + sy[2][w] + sy[3][w];
        float inv = 1.f / fmaxf((float)(end - beg), 1.f);
        float2 r;
        r.x = tx * inv;
        r.y = ty * inv;
        *(float2*)&out[(g << 7) + w * 2] = r;
    }
}

extern "C" void kernel_launch(void* const* d_in, const int* in_sizes, int n_in,
                              void* d_out, int out_size, void* d_ws, size_t ws_size,
                              hipStream_t stream) {
    const float* x0 = (const float*)d_in[0];
    const float* Wn = (const float*)d_in[1];
    const float* bn = (const float*)d_in[2];
    const float* Wr = (const float*)d_in[3];
    const float* gam = (const float*)d_in[4];
    const float* bet = (const float*)d_in[5];
    const int* ei = (const int*)d_in[6];
    const int* batch = (const int*)d_in[7];

    float* out = (float*)d_out;                 // [0,8192): graph_emb ; [8192,...): node_emb
    float* node_out = out + N_GRAPHS * HID;

    unsigned* ws = (unsigned*)d_ws;
    int* deg = (int*)(ws + WS_DEG);
    int* bsum = (int*)(ws + WS_BSUM);
    int* boff = (int*)(ws + WS_BOFF);
    int* offs = (int*)(ws + WS_OFFS);
    float* invdeg = (float*)(ws + WS_INVD);
    int* csr = (int*)(ws + WS_CSR);
    unsigned* hist = ws + WS_HIST;
    unsigned* agg16 = ws + WS_HIST;   // aliases hist (dead after fill)
    unsigned* xb16 = ws + WS_XB16;

    const int nb = (N_NODES + 255) / 256;          // 196
    k_cvt<<<(N_NODES * HID / 4) / 256, 256, 0, stream>>>((const float4*)x0, (uint2*)xb16);
    k_hist<<<HIST_BLOCKS, 256, 0, stream>>>(ei, hist);
    k_scanb<<<(NWORDS + 255) / 256, 256, 0, stream>>>(hist, deg);
    k_blockreduce<<<nb, 256, 0, stream>>>(deg, bsum);
    k_scanblocks<<<1, 256, 0, stream>>>(bsum, boff, nb);
    k_offsets<<<nb, 256, 0, stream>>>(deg, boff, offs, invdeg);
    k_fill2<<<HIST_BLOCKS * FILL_PASSES, 256, 0, stream>>>(ei, offs, hist, csr);

    const int gb = (N_NODES + 31) / 32;            // 1563

    for (int l = 0; l < 3; ++l) {
        k_aggx<<<(N_NODES / 4) * 8, 256, 0, stream>>>(xb16, csr, offs, deg, invdeg, agg16);
        k_gemm_ln<<<gb, 256, 0, stream>>>((const unsigned short*)agg16, (const unsigned short*)xb16,
                                          Wn + (size_t)l * HID * HID, Wr + (size_t)l * HID * HID,
                                          bn + (size_t)l * HID, gam + (size_t)l * HID,
                                          bet + (size_t)l * HID, node_out, xb16);
    }

    k_pool_seg<<<N_GRAPHS, 256, 0, stream>>>(xb16, batch, out);
}

// Round 6
// 619.197 us; speedup vs baseline: 1.8741x; 1.8741x over previous
//
#include <hip/hip_runtime.h>

#define N_NODES 50000
#define N_EDGES 1600000
#define HID     128
#define N_GRAPHS 64

#define HIST_BLOCKS 128
#define EPB (N_EDGES / HIST_BLOCKS)      // 12500 edges per block
#define NWORDS 25000                     // 50000 nodes packed 2-per-u32
#define FILL_PASSES 4
#define NPP 12500                        // nodes per fill pass
#define WPP (NPP / 2)                    // 6250 cursor words per pass

// workspace layout (4-byte words) — 8.15M words = 32.6 MB
#define WS_DEG   0u         // int[50000]
#define WS_BSUM  50000u     // int[256]
#define WS_BOFF  50256u     // int[256]
#define WS_OFFS  50512u     // int[50000]
#define WS_INVD  100512u    // float[50000]
#define WS_CSR   150512u    // int[1600000]
#define WS_HIST  1750512u   // uint[3200000] = hist[128][25000]; dead after fill -> aliased as agg16
#define WS_XB16  4950512u   // uint[3200000] (bf16 x2: 50000x128)
#define WS_END   8150512u

// ---- bf16 helpers (raw, RN-even pack; fp32 math everywhere) ----
__device__ __forceinline__ float bf_lo(unsigned u) { return __uint_as_float(u << 16); }
__device__ __forceinline__ float bf_hi(unsigned u) { return __uint_as_float(u & 0xffff0000u); }
__device__ __forceinline__ unsigned bf_rn(float f) {
    unsigned u = __float_as_uint(f);
    unsigned r = ((u >> 16) & 1u) + 0x7fffu;
    return (u + r) >> 16;
}
__device__ __forceinline__ unsigned bf_pack(float lo, float hi) {
    return bf_rn(lo) | (bf_rn(hi) << 16);
}

// ---------------- x0 fp32 -> bf16 ----------------
__global__ __launch_bounds__(256) void k_cvt(const float4* __restrict__ x, uint2* __restrict__ o) {
    int i = blockIdx.x * 256 + threadIdx.x;      // 1.6M total
    float4 v = x[i];
    uint2 r;
    r.x = bf_pack(v.x, v.y);
    r.y = bf_pack(v.z, v.w);
    o[i] = r;
}

// ---------------- CSR build: atomic-free (LDS histograms + block-partial scan) ----------------

// Stage 1: per-block LDS histogram of dst over its edge slice. Packed u16x2.
__global__ __launch_bounds__(256) void k_hist(const int* __restrict__ ei, unsigned* __restrict__ hist) {
    __shared__ unsigned sh[NWORDS];
    for (int i = threadIdx.x; i < NWORDS; i += 256) sh[i] = 0;
    __syncthreads();
    const int e0 = blockIdx.x * EPB;
    for (int i = threadIdx.x; i < EPB; i += 256) {
        int d = __builtin_nontemporal_load(ei + N_EDGES + e0 + i);
        atomicAdd(&sh[d >> 1], 1u << ((d & 1) << 4));
    }
    __syncthreads();
    unsigned* hb = hist + (size_t)blockIdx.x * NWORDS;
    for (int i = threadIdx.x; i < NWORDS; i += 256) hb[i] = sh[i];
}

// Stage 2: exclusive scan over the 128 block-partials per node (packed u16 scan).
__global__ __launch_bounds__(256) void k_scanb(unsigned* __restrict__ hist, int* __restrict__ deg) {
    int w = blockIdx.x * 256 + threadIdx.x;
    if (w >= NWORDS) return;
    unsigned run = 0;
#pragma unroll 8
    for (int b = 0; b < HIST_BLOCKS; ++b) {
        unsigned u = hist[(size_t)b * NWORDS + w];
        hist[(size_t)b * NWORDS + w] = run;
        run += u;
    }
    deg[2 * w] = (int)(run & 0xffffu);
    deg[2 * w + 1] = (int)(run >> 16);
}

__global__ __launch_bounds__(256) void k_blockreduce(const int* __restrict__ deg, int* __restrict__ bsum) {
    __shared__ int s[256];
    int i = blockIdx.x * 256 + threadIdx.x;
    s[threadIdx.x] = (i < N_NODES) ? deg[i] : 0;
    __syncthreads();
    for (int d = 128; d > 0; d >>= 1) {
        if (threadIdx.x < d) s[threadIdx.x] += s[threadIdx.x + d];
        __syncthreads();
    }
    if (threadIdx.x == 0) bsum[blockIdx.x] = s[0];
}

__global__ __launch_bounds__(256) void k_scanblocks(const int* __restrict__ bsum, int* __restrict__ boff, int nb) {
    __shared__ int s[256];
    int t = threadIdx.x;
    int v = (t < nb) ? bsum[t] : 0;
    s[t] = v;
    __syncthreads();
    for (int d = 1; d < 256; d <<= 1) {
        int add = (t >= d) ? s[t - d] : 0;
        __syncthreads();
        s[t] += add;
        __syncthreads();
    }
    if (t < nb) boff[t] = s[t] - v;   // exclusive
}

__global__ __launch_bounds__(256) void k_offsets(const int* __restrict__ deg, const int* __restrict__ boff,
                                                 int* __restrict__ offs, float* __restrict__ invdeg) {
    __shared__ int s[256];
    int b = blockIdx.x, t = threadIdx.x;
    int i = b * 256 + t;
    int v = (i < N_NODES) ? deg[i] : 0;
    s[t] = v;
    __syncthreads();
    for (int d = 1; d < 256; d <<= 1) {
        int add = (t >= d) ? s[t - d] : 0;
        __syncthreads();
        s[t] += add;
        __syncthreads();
    }
    if (i < N_NODES) {
        offs[i] = boff[b] + s[t] - v;   // exclusive global offset
        invdeg[i] = 1.0f / fmaxf((float)v, 1.0f);
    }
}

// Stage 3: fill — ALL 4 node-range passes concurrent in one 512-block dispatch.
// LDS atomics only. csr stores PRE-SCALED src uint4-offsets (src*16) so the
// gather kernel indexes uint4 rows directly.
__global__ __launch_bounds__(256) void k_fill2(const int* __restrict__ ei, const int* __restrict__ offs,
                                               const unsigned* __restrict__ hist, int* __restrict__ csr) {
    __shared__ unsigned scur[WPP];   // 25 KB
    const int s8 = blockIdx.x & 7;
    const int pass = s8 >> 1;                              // 0..3
    const int b = ((blockIdx.x >> 3) << 1) | (s8 & 1);     // 0..127 edge slice
    const int nbase = pass * NPP;
    const unsigned* hb = hist + (size_t)b * NWORDS + pass * WPP;
    for (int i = threadIdx.x; i < WPP; i += 256) scur[i] = hb[i];
    __syncthreads();
    const int e0 = b * EPB;
    for (int i = threadIdx.x; i < EPB; i += 256) {
        int d = __builtin_nontemporal_load(ei + N_EDGES + e0 + i);
        unsigned rd = (unsigned)(d - nbase);
        if (rd < (unsigned)NPP) {
            int s = ei[e0 + i];
            int sh = (rd & 1) << 4;
            unsigned old = atomicAdd(&scur[rd >> 1], 1u << sh);
            unsigned rel = (old >> sh) & 0xffffu;
            csr[offs[d] + (int)rel] = s * 16;   // pre-scaled uint4 row offset
        }
    }
}

// ---------------- per-layer: aggregation (quarter-wave per row, uint4 loads) ----------------
// One wave per node. 16 lanes x 16B = full 256B bf16 row per load instruction.
// 4 edge slots x 4 unroll = 16 rows in flight per wave. 8 fp32 accumulators.

__global__ __launch_bounds__(256) void k_agg4(const uint4* __restrict__ xb, const int* __restrict__ csr,
                                              const int* __restrict__ offs, const int* __restrict__ deg,
                                              const float* __restrict__ invdeg, uint4* __restrict__ agg) {
    const int node = blockIdx.x * 4 + (threadIdx.x >> 6);
    const int lane = threadIdx.x & 63;
    const int slot = lane >> 4;        // edge slot 0..3
    const int m = lane & 15;           // uint4 index within row
    const int beg = offs[node];
    const int dn = deg[node];
    const uint4* xm = xb + m;
    float a0 = 0.f, a1 = 0.f, a2 = 0.f, a3 = 0.f, a4 = 0.f, a5 = 0.f, a6 = 0.f, a7 = 0.f;
    int j = slot;
    for (; j + 16 <= dn; j += 16) {
        int s0 = csr[beg + j];
        int s1 = csr[beg + j + 4];
        int s2 = csr[beg + j + 8];
        int s3 = csr[beg + j + 12];
        uint4 u0 = xm[s0];
        uint4 u1 = xm[s1];
        uint4 u2 = xm[s2];
        uint4 u3 = xm[s3];
        a0 += (bf_lo(u0.x) + bf_lo(u1.x)) + (bf_lo(u2.x) + bf_lo(u3.x));
        a1 += (bf_hi(u0.x) + bf_hi(u1.x)) + (bf_hi(u2.x) + bf_hi(u3.x));
        a2 += (bf_lo(u0.y) + bf_lo(u1.y)) + (bf_lo(u2.y) + bf_lo(u3.y));
        a3 += (bf_hi(u0.y) + bf_hi(u1.y)) + (bf_hi(u2.y) + bf_hi(u3.y));
        a4 += (bf_lo(u0.z) + bf_lo(u1.z)) + (bf_lo(u2.z) + bf_lo(u3.z));
        a5 += (bf_hi(u0.z) + bf_hi(u1.z)) + (bf_hi(u2.z) + bf_hi(u3.z));
        a6 += (bf_lo(u0.w) + bf_lo(u1.w)) + (bf_lo(u2.w) + bf_lo(u3.w));
        a7 += (bf_hi(u0.w) + bf_hi(u1.w)) + (bf_hi(u2.w) + bf_hi(u3.w));
    }
    for (; j < dn; j += 4) {
        uint4 u0 = xm[csr[beg + j]];
        a0 += bf_lo(u0.x); a1 += bf_hi(u0.x);
        a2 += bf_lo(u0.y); a3 += bf_hi(u0.y);
        a4 += bf_lo(u0.z); a5 += bf_hi(u0.z);
        a6 += bf_lo(u0.w); a7 += bf_hi(u0.w);
    }
#pragma unroll
    for (int msk = 16; msk < 64; msk <<= 1) {
        a0 += __shfl_xor(a0, msk); a1 += __shfl_xor(a1, msk);
        a2 += __shfl_xor(a2, msk); a3 += __shfl_xor(a3, msk);
        a4 += __shfl_xor(a4, msk); a5 += __shfl_xor(a5, msk);
        a6 += __shfl_xor(a6, msk); a7 += __shfl_xor(a7, msk);
    }
    if (slot == 0) {
        float id = invdeg[node];
        uint4 r;
        r.x = bf_pack(a0 * id, a1 * id);
        r.y = bf_pack(a2 * id, a3 * id);
        r.z = bf_pack(a4 * id, a5 * id);
        r.w = bf_pack(a6 * id, a7 * id);
        agg[node * 16 + m] = r;
    }
}

// ---------------- per-layer: fused (agg@Wn + x@Wr + bn) -> LN -> ReLU ----------------

__global__ __launch_bounds__(256) void k_gemm_ln(
        const unsigned short* __restrict__ aggb, const unsigned short* __restrict__ xinb,
        const float* __restrict__ Wn, const float* __restrict__ Wr,
        const float* __restrict__ bn, const float* __restrict__ gam,
        const float* __restrict__ bet, float* __restrict__ xout,
        unsigned* __restrict__ b16out) {
    __shared__ float smem[32 * 36 + 32 * 128];   // 5248 floats = 21 KB
    float* A_lds = smem;            // [k][r] stride 36
    float* W_lds = smem + 32 * 36;  // [k][c] stride 128
    float* H = smem;                // [r][c] stride 132, aliases (4224 <= 5248)

    const int t = threadIdx.x;
    const int tx = t & 31;   // col group: cols tx*4 .. tx*4+3
    const int ty = t >> 5;   // row group: rows ty*4 .. ty*4+3
    const int row0 = blockIdx.x * 32;

    float acc[4][4];
#pragma unroll
    for (int i = 0; i < 4; i++)
#pragma unroll
        for (int j = 0; j < 4; j++) acc[i][j] = 0.f;

    for (int pass = 0; pass < 2; ++pass) {
        const unsigned short* A = pass ? xinb : aggb;
        const float* W = pass ? Wr : Wn;
        for (int k0 = 0; k0 < HID; k0 += 32) {
            __syncthreads();
            {   // stage A transposed (bf16 -> fp32): kk = t&31, rbase = t>>5 (+i*8)
                int kk = t & 31;
                int rb = t >> 5;
#pragma unroll
                for (int i = 0; i < 4; i++) {
                    int r = rb + i * 8;
                    int gr = row0 + r;
                    unsigned short raw = (gr < N_NODES) ? A[(size_t)gr * HID + k0 + kk] : (unsigned short)0;
                    A_lds[kk * 36 + r] = __uint_as_float(((unsigned)raw) << 16);
                }
            }
            {   // stage W: 32x128 = 4096 elems, 16 per thread, coalesced
#pragma unroll
                for (int i = 0; i < 16; i++) {
                    int idx = t + i * 256;
                    int kk = idx >> 7;
                    int c = idx & 127;
                    W_lds[idx] = W[(size_t)(k0 + kk) * HID + c];
                }
            }
            __syncthreads();
#pragma unroll
            for (int k = 0; k < 32; k++) {
                float4 a4 = *(const float4*)&A_lds[k * 36 + ty * 4];
                float4 w4 = *(const float4*)&W_lds[(k << 7) + tx * 4];
                float av[4] = {a4.x, a4.y, a4.z, a4.w};
                float wv[4] = {w4.x, w4.y, w4.z, w4.w};
#pragma unroll
                for (int i = 0; i < 4; i++)
#pragma unroll
                    for (int j = 0; j < 4; j++) acc[i][j] = fmaf(av[i], wv[j], acc[i][j]);
            }
        }
    }

    // epilogue: bias -> H (LDS) -> LayerNorm -> ReLU -> store fp32 + bf16
    __syncthreads();
    float4 b4 = *(const float4*)&bn[tx * 4];
#pragma unroll
    for (int i = 0; i < 4; i++) {
        float4 h4;
        h4.x = acc[i][0] + b4.x;
        h4.y = acc[i][1] + b4.y;
        h4.z = acc[i][2] + b4.z;
        h4.w = acc[i][3] + b4.w;
        *(float4*)&H[(ty * 4 + i) * 132 + tx * 4] = h4;
    }
    __syncthreads();

    int row = t >> 3;    // 0..31
    int sub = t & 7;     // 8 threads per row, 16 cols each
    const float* hr = &H[row * 132 + sub * 16];
    float v[16];
    float s = 0.f, s2 = 0.f;
#pragma unroll
    for (int i = 0; i < 16; i++) {
        v[i] = hr[i];
        s += v[i];
        s2 += v[i] * v[i];
    }
#pragma unroll
    for (int m = 1; m < 8; m <<= 1) {
        s += __shfl_xor(s, m);
        s2 += __shfl_xor(s2, m);
    }
    float mean = s * (1.f / 128.f);
    float var = s2 * (1.f / 128.f) - mean * mean;
    float rstd = rsqrtf(var + 1e-5f);
    int gr = row0 + row;
    if (gr < N_NODES) {
        int cb = sub * 16;
        float o[16];
#pragma unroll
        for (int i = 0; i < 16; i++) {
            int c = cb + i;
            o[i] = fmaxf((v[i] - mean) * rstd * gam[c] + bet[c], 0.f);
            xout[(size_t)gr * HID + c] = o[i];
        }
#pragma unroll
        for (int i = 0; i < 16; i += 2)
            b16out[(size_t)gr * 64 + ((cb + i) >> 1)] = bf_pack(o[i], o[i + 1]);
    }
}

// ---------------- graph mean-pool: atomic-free segmented reduction (bf16 input) ----------------

__global__ __launch_bounds__(256) void k_pool_seg(const unsigned* __restrict__ xb,
                                                  const int* __restrict__ batch,
                                                  float* __restrict__ out) {
    const int g = blockIdx.x;          // 0..63
    __shared__ int s_beg, s_end;
    if (threadIdx.x == 0) {
        int lo = 0, hi = N_NODES;
        while (lo < hi) { int mid = (lo + hi) >> 1; if (batch[mid] < g) lo = mid + 1; else hi = mid; }
        s_beg = lo;
        lo = 0; hi = N_NODES;
        while (lo < hi) { int mid = (lo + hi) >> 1; if (batch[mid] < g + 1) lo = mid + 1; else hi = mid; }
        s_end = lo;
    }
    __syncthreads();
    const int beg = s_beg, end = s_end;
    const int w = threadIdx.x & 63;    // u32 word (2 cols)
    const int q = threadIdx.x >> 6;    // row group 0..3
    float ax = 0.f, ay = 0.f;
    for (int r = beg + q; r < end; r += 4) {
        unsigned u = xb[(size_t)r * 64 + w];
        ax += bf_lo(u);
        ay += bf_hi(u);
    }
    __shared__ float sx[4][64], sy[4][64];
    sx[q][w] = ax;
    sy[q][w] = ay;
    __syncthreads();
    if (q == 0) {
        float tx = sx[0][w] + sx[1][w] + sx[2][w] + sx[3][w];
        float ty = sy[0][w] + sy[1][w] + sy[2][w] + sy[3][w];
        float inv = 1.f / fmaxf((float)(end - beg), 1.f);
        float2 r;
        r.x = tx * inv;
        r.y = ty * inv;
        *(float2*)&out[(g << 7) + w * 2] = r;
    }
}

extern "C" void kernel_launch(void* const* d_in, const int* in_sizes, int n_in,
                              void* d_out, int out_size, void* d_ws, size_t ws_size,
                              hipStream_t stream) {
    const float* x0 = (const float*)d_in[0];
    const float* Wn = (const float*)d_in[1];
    const float* bn = (const float*)d_in[2];
    const float* Wr = (const float*)d_in[3];
    const float* gam = (const float*)d_in[4];
    const float* bet = (const float*)d_in[5];
    const int* ei = (const int*)d_in[6];
    const int* batch = (const int*)d_in[7];

    float* out = (float*)d_out;                 // [0,8192): graph_emb ; [8192,...): node_emb
    float* node_out = out + N_GRAPHS * HID;

    unsigned* ws = (unsigned*)d_ws;
    int* deg = (int*)(ws + WS_DEG);
    int* bsum = (int*)(ws + WS_BSUM);
    int* boff = (int*)(ws + WS_BOFF);
    int* offs = (int*)(ws + WS_OFFS);
    float* invdeg = (float*)(ws + WS_INVD);
    int* csr = (int*)(ws + WS_CSR);
    unsigned* hist = ws + WS_HIST;
    unsigned* agg16 = ws + WS_HIST;   // aliases hist (dead after fill)
    unsigned* xb16 = ws + WS_XB16;

    const int nb = (N_NODES + 255) / 256;          // 196
    k_cvt<<<(N_NODES * HID / 4) / 256, 256, 0, stream>>>((const float4*)x0, (uint2*)xb16);
    k_hist<<<HIST_BLOCKS, 256, 0, stream>>>(ei, hist);
    k_scanb<<<(NWORDS + 255) / 256, 256, 0, stream>>>(hist, deg);
    k_blockreduce<<<nb, 256, 0, stream>>>(deg, bsum);
    k_scanblocks<<<1, 256, 0, stream>>>(bsum, boff, nb);
    k_offsets<<<nb, 256, 0, stream>>>(deg, boff, offs, invdeg);
    k_fill2<<<HIST_BLOCKS * FILL_PASSES, 256, 0, stream>>>(ei, offs, hist, csr);

    const int gb = (N_NODES + 31) / 32;            // 1563

    for (int l = 0; l < 3; ++l) {
        k_agg4<<<N_NODES / 4, 256, 0, stream>>>((const uint4*)xb16, csr, offs, deg, invdeg, (uint4*)agg16);
        k_gemm_ln<<<gb, 256, 0, stream>>>((const unsigned short*)agg16, (const unsigned short*)xb16,
                                          Wn + (size_t)l * HID * HID, Wr + (size_t)l * HID * HID,
                                          bn + (size_t)l * HID, gam + (size_t)l * HID,
                                          bet + (size_t)l * HID, node_out, xb16);
    }

    k_pool_seg<<<N_GRAPHS, 256, 0, stream>>>(xb16, batch, out);
}

// Round 7
// 526.465 us; speedup vs baseline: 2.2042x; 1.1761x over previous
//
#include <hip/hip_runtime.h>

#define N_NODES 50000
#define N_EDGES 1600000
#define HID     128
#define N_GRAPHS 64

#define HIST_BLOCKS 128
#define EPB (N_EDGES / HIST_BLOCKS)      // 12500 edges per block
#define NWORDS 25000                     // 50000 nodes packed 2-per-u32
#define FILL_PASSES 4
#define NPP 12500                        // nodes per fill pass
#define WPP (NPP / 2)                    // 6250 cursor words per pass

// workspace layout (4-byte words) — 8.2M words = 32.8 MB
#define WS_DEG   0u         // int[50000]
#define WS_BSUM  50000u     // int[256]
#define WS_BOFF  50256u     // int[256]
#define WS_OFFS  50512u     // int[50000]
#define WS_INVD  100512u    // float[50000]
#define WS_CSR   150512u    // int[1600000]
#define WS_HIST  1750512u   // uint[3200000] = hist[128][25000]; dead after fill -> aliased as agg16
#define WS_XB16  4950512u   // uint[3200000] (bf16 x2: 50000x128)
#define WS_WP    8150512u   // uint[49152] = packed W frags: 3 layers x 4096 uint4
#define WS_END   8199664u

typedef __attribute__((ext_vector_type(8))) short short8;
typedef __attribute__((ext_vector_type(4))) float floatx4;

// ---- bf16 helpers (raw, RN-even pack; fp32 math everywhere) ----
__device__ __forceinline__ float bf_lo(unsigned u) { return __uint_as_float(u << 16); }
__device__ __forceinline__ float bf_hi(unsigned u) { return __uint_as_float(u & 0xffff0000u); }
__device__ __forceinline__ unsigned bf_rn(float f) {
    unsigned u = __float_as_uint(f);
    unsigned r = ((u >> 16) & 1u) + 0x7fffu;
    return (u + r) >> 16;
}
__device__ __forceinline__ unsigned bf_pack(float lo, float hi) {
    return bf_rn(lo) | (bf_rn(hi) << 16);
}

// ---------------- x0 fp32 -> bf16 ----------------
__global__ __launch_bounds__(256) void k_cvt(const float4* __restrict__ x, uint2* __restrict__ o) {
    int i = blockIdx.x * 256 + threadIdx.x;      // 1.6M total
    float4 v = x[i];
    uint2 r;
    r.x = bf_pack(v.x, v.y);
    r.y = bf_pack(v.z, v.w);
    o[i] = r;
}

// ---------------- W pre-pack into MFMA B-fragment order ----------------
// Wp[layer][kblk][n][quad] = uint4 holding bf16 frag[j]=B[kblk*32+quad*8+j][n],
// where B = [Wn; Wr] (K=256). One-time, 12288 uint4.
__global__ __launch_bounds__(256) void k_packw(const float* __restrict__ Wn, const float* __restrict__ Wr,
                                               uint4* __restrict__ wp) {
    int idx = blockIdx.x * 256 + threadIdx.x;    // 12288 total
    int layer = idx >> 12;
    int rem = idx & 4095;
    int kb = rem >> 9;
    int n = (rem >> 2) & 127;
    int quad = rem & 3;
    float v[8];
#pragma unroll
    for (int j = 0; j < 8; j++) {
        int k = kb * 32 + quad * 8 + j;
        v[j] = (k < 128) ? Wn[layer * 16384 + k * 128 + n]
                         : Wr[layer * 16384 + (k - 128) * 128 + n];
    }
    uint4 r;
    r.x = bf_pack(v[0], v[1]);
    r.y = bf_pack(v[2], v[3]);
    r.z = bf_pack(v[4], v[5]);
    r.w = bf_pack(v[6], v[7]);
    wp[idx] = r;
}

// ---------------- CSR build: atomic-free (LDS histograms + block-partial scan) ----------------

__global__ __launch_bounds__(256) void k_hist(const int* __restrict__ ei, unsigned* __restrict__ hist) {
    __shared__ unsigned sh[NWORDS];
    for (int i = threadIdx.x; i < NWORDS; i += 256) sh[i] = 0;
    __syncthreads();
    const int e0 = blockIdx.x * EPB;
    for (int i = threadIdx.x; i < EPB; i += 256) {
        int d = __builtin_nontemporal_load(ei + N_EDGES + e0 + i);
        atomicAdd(&sh[d >> 1], 1u << ((d & 1) << 4));
    }
    __syncthreads();
    unsigned* hb = hist + (size_t)blockIdx.x * NWORDS;
    for (int i = threadIdx.x; i < NWORDS; i += 256) hb[i] = sh[i];
}

__global__ __launch_bounds__(256) void k_scanb(unsigned* __restrict__ hist, int* __restrict__ deg) {
    int w = blockIdx.x * 256 + threadIdx.x;
    if (w >= NWORDS) return;
    unsigned run = 0;
#pragma unroll 8
    for (int b = 0; b < HIST_BLOCKS; ++b) {
        unsigned u = hist[(size_t)b * NWORDS + w];
        hist[(size_t)b * NWORDS + w] = run;
        run += u;
    }
    deg[2 * w] = (int)(run & 0xffffu);
    deg[2 * w + 1] = (int)(run >> 16);
}

__global__ __launch_bounds__(256) void k_blockreduce(const int* __restrict__ deg, int* __restrict__ bsum) {
    __shared__ int s[256];
    int i = blockIdx.x * 256 + threadIdx.x;
    s[threadIdx.x] = (i < N_NODES) ? deg[i] : 0;
    __syncthreads();
    for (int d = 128; d > 0; d >>= 1) {
        if (threadIdx.x < d) s[threadIdx.x] += s[threadIdx.x + d];
        __syncthreads();
    }
    if (threadIdx.x == 0) bsum[blockIdx.x] = s[0];
}

__global__ __launch_bounds__(256) void k_scanblocks(const int* __restrict__ bsum, int* __restrict__ boff, int nb) {
    __shared__ int s[256];
    int t = threadIdx.x;
    int v = (t < nb) ? bsum[t] : 0;
    s[t] = v;
    __syncthreads();
    for (int d = 1; d < 256; d <<= 1) {
        int add = (t >= d) ? s[t - d] : 0;
        __syncthreads();
        s[t] += add;
        __syncthreads();
    }
    if (t < nb) boff[t] = s[t] - v;   // exclusive
}

__global__ __launch_bounds__(256) void k_offsets(const int* __restrict__ deg, const int* __restrict__ boff,
                                                 int* __restrict__ offs, float* __restrict__ invdeg) {
    __shared__ int s[256];
    int b = blockIdx.x, t = threadIdx.x;
    int i = b * 256 + t;
    int v = (i < N_NODES) ? deg[i] : 0;
    s[t] = v;
    __syncthreads();
    for (int d = 1; d < 256; d <<= 1) {
        int add = (t >= d) ? s[t - d] : 0;
        __syncthreads();
        s[t] += add;
        __syncthreads();
    }
    if (i < N_NODES) {
        offs[i] = boff[b] + s[t] - v;   // exclusive global offset
        invdeg[i] = 1.0f / fmaxf((float)v, 1.0f);
    }
}

// Stage 3: fill — all 4 node-range passes concurrent; LDS atomics only.
// csr stores PRE-SCALED src uint4-offsets (src*16).
__global__ __launch_bounds__(256) void k_fill2(const int* __restrict__ ei, const int* __restrict__ offs,
                                               const unsigned* __restrict__ hist, int* __restrict__ csr) {
    __shared__ unsigned scur[WPP];   // 25 KB
    const int s8 = blockIdx.x & 7;
    const int pass = s8 >> 1;                              // 0..3
    const int b = ((blockIdx.x >> 3) << 1) | (s8 & 1);     // 0..127 edge slice
    const int nbase = pass * NPP;
    const unsigned* hb = hist + (size_t)b * NWORDS + pass * WPP;
    for (int i = threadIdx.x; i < WPP; i += 256) scur[i] = hb[i];
    __syncthreads();
    const int e0 = b * EPB;
    for (int i = threadIdx.x; i < EPB; i += 256) {
        int d = __builtin_nontemporal_load(ei + N_EDGES + e0 + i);
        unsigned rd = (unsigned)(d - nbase);
        if (rd < (unsigned)NPP) {
            int s = ei[e0 + i];
            int sh = (rd & 1) << 4;
            unsigned old = atomicAdd(&scur[rd >> 1], 1u << sh);
            unsigned rel = (old >> sh) & 0xffffu;
            csr[offs[d] + (int)rel] = s * 16;   // pre-scaled uint4 row offset
        }
    }
}

// ---------------- per-layer: aggregation (quarter-wave per row, uint4 loads) ----------------

__global__ __launch_bounds__(256) void k_agg4(const uint4* __restrict__ xb, const int* __restrict__ csr,
                                              const int* __restrict__ offs, const int* __restrict__ deg,
                                              const float* __restrict__ invdeg, uint4* __restrict__ agg) {
    const int node = blockIdx.x * 4 + (threadIdx.x >> 6);
    const int lane = threadIdx.x & 63;
    const int slot = lane >> 4;        // edge slot 0..3
    const int m = lane & 15;           // uint4 index within row
    const int beg = offs[node];
    const int dn = deg[node];
    const uint4* xm = xb + m;
    float a0 = 0.f, a1 = 0.f, a2 = 0.f, a3 = 0.f, a4 = 0.f, a5 = 0.f, a6 = 0.f, a7 = 0.f;
    int j = slot;
    for (; j + 16 <= dn; j += 16) {
        int s0 = csr[beg + j];
        int s1 = csr[beg + j + 4];
        int s2 = csr[beg + j + 8];
        int s3 = csr[beg + j + 12];
        uint4 u0 = xm[s0];
        uint4 u1 = xm[s1];
        uint4 u2 = xm[s2];
        uint4 u3 = xm[s3];
        a0 += (bf_lo(u0.x) + bf_lo(u1.x)) + (bf_lo(u2.x) + bf_lo(u3.x));
        a1 += (bf_hi(u0.x) + bf_hi(u1.x)) + (bf_hi(u2.x) + bf_hi(u3.x));
        a2 += (bf_lo(u0.y) + bf_lo(u1.y)) + (bf_lo(u2.y) + bf_lo(u3.y));
        a3 += (bf_hi(u0.y) + bf_hi(u1.y)) + (bf_hi(u2.y) + bf_hi(u3.y));
        a4 += (bf_lo(u0.z) + bf_lo(u1.z)) + (bf_lo(u2.z) + bf_lo(u3.z));
        a5 += (bf_hi(u0.z) + bf_hi(u1.z)) + (bf_hi(u2.z) + bf_hi(u3.z));
        a6 += (bf_lo(u0.w) + bf_lo(u1.w)) + (bf_lo(u2.w) + bf_lo(u3.w));
        a7 += (bf_hi(u0.w) + bf_hi(u1.w)) + (bf_hi(u2.w) + bf_hi(u3.w));
    }
    for (; j < dn; j += 4) {
        uint4 u0 = xm[csr[beg + j]];
        a0 += bf_lo(u0.x); a1 += bf_hi(u0.x);
        a2 += bf_lo(u0.y); a3 += bf_hi(u0.y);
        a4 += bf_lo(u0.z); a5 += bf_hi(u0.z);
        a6 += bf_lo(u0.w); a7 += bf_hi(u0.w);
    }
#pragma unroll
    for (int msk = 16; msk < 64; msk <<= 1) {
        a0 += __shfl_xor(a0, msk); a1 += __shfl_xor(a1, msk);
        a2 += __shfl_xor(a2, msk); a3 += __shfl_xor(a3, msk);
        a4 += __shfl_xor(a4, msk); a5 += __shfl_xor(a5, msk);
        a6 += __shfl_xor(a6, msk); a7 += __shfl_xor(a7, msk);
    }
    if (slot == 0) {
        float id = invdeg[node];
        uint4 r;
        r.x = bf_pack(a0 * id, a1 * id);
        r.y = bf_pack(a2 * id, a3 * id);
        r.z = bf_pack(a4 * id, a5 * id);
        r.w = bf_pack(a6 * id, a7 * id);
        agg[node * 16 + m] = r;
    }
}

// ---------------- per-layer: MFMA GEMM (K=256: [agg|x] @ [Wn;Wr]) + bias + LN + ReLU ----------------
// Block: 32 rows x 128 cols, 4 waves; wave w owns cols w*32..w*32+31.
// A-frags direct from bf16 global rows (lane m=lane&15, quad k-group) — no staging.
// B-frags from pre-packed wp. C/D: col=lane&15, row=quad*4+reg (m89/m91-verified).
// LDS only for LN H round-trip. fp32 node_emb written on last layer only.

__global__ __launch_bounds__(256) void k_gemm_mfma(
        const uint4* __restrict__ aggq, const uint4* __restrict__ xq,
        const uint4* __restrict__ wp, const float* __restrict__ bn,
        const float* __restrict__ gam, const float* __restrict__ bet,
        float* __restrict__ xout, unsigned* __restrict__ b16out, int write_f32) {
    __shared__ float H[32 * 132];   // 16.9 KB
    const int t = threadIdx.x;
    const int wave = t >> 6;
    const int lane = t & 63;
    const int quad = lane >> 4;
    const int nl = lane & 15;
    const int row0 = blockIdx.x * 32;
    const int nb = wave * 32;

    // A row indices (clamped for the 16-row overhang of the last block)
    int r0 = row0 + nl;
    int r1 = row0 + 16 + nl;
    if (r0 >= N_NODES) r0 = N_NODES - 1;
    if (r1 >= N_NODES) r1 = N_NODES - 1;

    floatx4 acc00 = {0.f, 0.f, 0.f, 0.f}, acc01 = acc00, acc10 = acc00, acc11 = acc00;

#pragma unroll
    for (int kb = 0; kb < 8; ++kb) {
        const uint4* Asrc = (kb < 4) ? aggq : xq;
        const int kk = kb & 3;
        uint4 a0 = Asrc[r0 * 16 + kk * 4 + quad];
        uint4 a1 = Asrc[r1 * 16 + kk * 4 + quad];
        uint4 b0 = wp[(kb * 128 + nb + nl) * 4 + quad];
        uint4 b1 = wp[(kb * 128 + nb + 16 + nl) * 4 + quad];
        short8 a0s = *(short8*)&a0, a1s = *(short8*)&a1;
        short8 b0s = *(short8*)&b0, b1s = *(short8*)&b1;
        acc00 = __builtin_amdgcn_mfma_f32_16x16x32_bf16(a0s, b0s, acc00, 0, 0, 0);
        acc01 = __builtin_amdgcn_mfma_f32_16x16x32_bf16(a0s, b1s, acc01, 0, 0, 0);
        acc10 = __builtin_amdgcn_mfma_f32_16x16x32_bf16(a1s, b0s, acc10, 0, 0, 0);
        acc11 = __builtin_amdgcn_mfma_f32_16x16x32_bf16(a1s, b1s, acc11, 0, 0, 0);
    }

    // bias + scatter to H (LDS): row = mt*16 + quad*4 + reg; col = nb + nt*16 + nl
    float bn0 = bn[nb + nl];
    float bn1 = bn[nb + 16 + nl];
#pragma unroll
    for (int reg = 0; reg < 4; ++reg) {
        int rr = quad * 4 + reg;
        H[rr * 132 + nb + nl] = acc00[reg] + bn0;
        H[rr * 132 + nb + 16 + nl] = acc01[reg] + bn1;
        H[(16 + rr) * 132 + nb + nl] = acc10[reg] + bn0;
        H[(16 + rr) * 132 + nb + 16 + nl] = acc11[reg] + bn1;
    }
    __syncthreads();

    // LayerNorm + ReLU: 8 threads per row, 16 cols each
    int row = t >> 3;    // 0..31
    int sub = t & 7;
    const float* hr = &H[row * 132 + sub * 16];
    float v[16];
    float s = 0.f, s2 = 0.f;
#pragma unroll
    for (int i = 0; i < 16; i++) {
        v[i] = hr[i];
        s += v[i];
        s2 += v[i] * v[i];
    }
#pragma unroll
    for (int m = 1; m < 8; m <<= 1) {
        s += __shfl_xor(s, m);
        s2 += __shfl_xor(s2, m);
    }
    float mean = s * (1.f / 128.f);
    float var = s2 * (1.f / 128.f) - mean * mean;
    float rstd = rsqrtf(var + 1e-5f);
    int gr = row0 + row;
    if (gr < N_NODES) {
        int cb = sub * 16;
        float o[16];
#pragma unroll
        for (int i = 0; i < 16; i++) {
            int c = cb + i;
            o[i] = fmaxf((v[i] - mean) * rstd * gam[c] + bet[c], 0.f);
        }
        if (write_f32) {
#pragma unroll
            for (int i = 0; i < 16; i += 4)
                *(float4*)&xout[(size_t)gr * HID + cb + i] = *(float4*)&o[i];
        }
        unsigned p[8];
#pragma unroll
        for (int i = 0; i < 8; i++) p[i] = bf_pack(o[2 * i], o[2 * i + 1]);
        *(uint4*)&b16out[(size_t)gr * 64 + (cb >> 1)] = *(uint4*)&p[0];
        *(uint4*)&b16out[(size_t)gr * 64 + (cb >> 1) + 4] = *(uint4*)&p[4];
    }
}

// ---------------- graph mean-pool: atomic-free segmented reduction (bf16 input) ----------------

__global__ __launch_bounds__(256) void k_pool_seg(const unsigned* __restrict__ xb,
                                                  const int* __restrict__ batch,
                                                  float* __restrict__ out) {
    const int g = blockIdx.x;          // 0..63
    __shared__ int s_beg, s_end;
    if (threadIdx.x == 0) {
        int lo = 0, hi = N_NODES;
        while (lo < hi) { int mid = (lo + hi) >> 1; if (batch[mid] < g) lo = mid + 1; else hi = mid; }
        s_beg = lo;
        lo = 0; hi = N_NODES;
        while (lo < hi) { int mid = (lo + hi) >> 1; if (batch[mid] < g + 1) lo = mid + 1; else hi = mid; }
        s_end = lo;
    }
    __syncthreads();
    const int beg = s_beg, end = s_end;
    const int w = threadIdx.x & 63;    // u32 word (2 cols)
    const int q = threadIdx.x >> 6;    // row group 0..3
    float ax = 0.f, ay = 0.f;
    for (int r = beg + q; r < end; r += 4) {
        unsigned u = xb[(size_t)r * 64 + w];
        ax += bf_lo(u);
        ay += bf_hi(u);
    }
    __shared__ float sx[4][64], sy[4][64];
    sx[q][w] = ax;
    sy[q][w] = ay;
    __syncthreads();
    if (q == 0) {
        float tx = sx[0][w] + sx[1][w] + sx[2][w] + sx[3][w];
        float ty = sy[0][w] + sy[1][w] + sy[2][w] + sy[3][w];
        float inv = 1.f / fmaxf((float)(end - beg), 1.f);
        float2 r;
        r.x = tx * inv;
        r.y = ty * inv;
        *(float2*)&out[(g << 7) + w * 2] = r;
    }
}

extern "C" void kernel_launch(void* const* d_in, const int* in_sizes, int n_in,
                              void* d_out, int out_size, void* d_ws, size_t ws_size,
                              hipStream_t stream) {
    const float* x0 = (const float*)d_in[0];
    const float* Wn = (const float*)d_in[1];
    const float* bn = (const float*)d_in[2];
    const float* Wr = (const float*)d_in[3];
    const float* gam = (const float*)d_in[4];
    const float* bet = (const float*)d_in[5];
    const int* ei = (const int*)d_in[6];
    const int* batch = (const int*)d_in[7];

    float* out = (float*)d_out;                 // [0,8192): graph_emb ; [8192,...): node_emb
    float* node_out = out + N_GRAPHS * HID;

    unsigned* ws = (unsigned*)d_ws;
    int* deg = (int*)(ws + WS_DEG);
    int* bsum = (int*)(ws + WS_BSUM);
    int* boff = (int*)(ws + WS_BOFF);
    int* offs = (int*)(ws + WS_OFFS);
    float* invdeg = (float*)(ws + WS_INVD);
    int* csr = (int*)(ws + WS_CSR);
    unsigned* hist = ws + WS_HIST;
    unsigned* agg16 = ws + WS_HIST;   // aliases hist (dead after fill)
    unsigned* xb16 = ws + WS_XB16;
    uint4* wp = (uint4*)(ws + WS_WP);

    const int nb = (N_NODES + 255) / 256;          // 196
    k_cvt<<<(N_NODES * HID / 4) / 256, 256, 0, stream>>>((const float4*)x0, (uint2*)xb16);
    k_packw<<<48, 256, 0, stream>>>(Wn, Wr, wp);
    k_hist<<<HIST_BLOCKS, 256, 0, stream>>>(ei, hist);
    k_scanb<<<(NWORDS + 255) / 256, 256, 0, stream>>>(hist, deg);
    k_blockreduce<<<nb, 256, 0, stream>>>(deg, bsum);
    k_scanblocks<<<1, 256, 0, stream>>>(bsum, boff, nb);
    k_offsets<<<nb, 256, 0, stream>>>(deg, boff, offs, invdeg);
    k_fill2<<<HIST_BLOCKS * FILL_PASSES, 256, 0, stream>>>(ei, offs, hist, csr);

    const int gb = (N_NODES + 31) / 32;            // 1563

    for (int l = 0; l < 3; ++l) {
        k_agg4<<<N_NODES / 4, 256, 0, stream>>>((const uint4*)xb16, csr, offs, deg, invdeg, (uint4*)agg16);
        k_gemm_mfma<<<gb, 256, 0, stream>>>((const uint4*)agg16, (const uint4*)xb16,
                                            wp + (size_t)l * 4096, bn + (size_t)l * HID,
                                            gam + (size_t)l * HID, bet + (size_t)l * HID,
                                            node_out, xb16, l == 2 ? 1 : 0);
    }

    k_pool_seg<<<N_GRAPHS, 256, 0, stream>>>(xb16, batch, out);
}

// Round 8
// 482.416 us; speedup vs baseline: 2.4055x; 1.0913x over previous
//
#include <hip/hip_runtime.h>

#define N_NODES 50000
#define N_EDGES 1600000
#define HID     128
#define N_GRAPHS 64

#define HIST_BLOCKS 128
#define EPB (N_EDGES / HIST_BLOCKS)      // 12500 edges per block
#define NWORDS 25000                     // 50000 nodes packed 2-per-u32
#define FILL_PASSES 4
#define NPP 12500                        // nodes per fill pass
#define WPP (NPP / 2)                    // 6250 cursor words per pass

// workspace layout (4-byte words) — 8.2M words = 32.8 MB
#define WS_DEG   0u         // int[50000]
#define WS_BSUM  50000u     // int[256]
#define WS_BOFF  50256u     // int[256]
#define WS_OFFS  50512u     // int[50000]
#define WS_INVD  100512u    // float[50000]
#define WS_CSR   150512u    // int[1600000]
#define WS_XB_B  1750512u   // uint[3200000]: hist[128][25000] during build; x ping buffer B after
#define WS_XB_A  4950512u   // uint[3200000]: x ping buffer A (bf16 x2: 50000x128)
#define WS_WP    8150512u   // uint[49152] = packed W frags: 3 layers x 4096 uint4
#define WS_END   8199664u

typedef __attribute__((ext_vector_type(8))) short short8;
typedef __attribute__((ext_vector_type(4))) float floatx4;

// ---- bf16 helpers (raw, RN-even pack; fp32 math everywhere) ----
__device__ __forceinline__ float bf_lo(unsigned u) { return __uint_as_float(u << 16); }
__device__ __forceinline__ float bf_hi(unsigned u) { return __uint_as_float(u & 0xffff0000u); }
__device__ __forceinline__ unsigned bf_rn(float f) {
    unsigned u = __float_as_uint(f);
    unsigned r = ((u >> 16) & 1u) + 0x7fffu;
    return (u + r) >> 16;
}
__device__ __forceinline__ unsigned bf_pack(float lo, float hi) {
    return bf_rn(lo) | (bf_rn(hi) << 16);
}

// ---------------- x0 fp32 -> bf16 ----------------
__global__ __launch_bounds__(256) void k_cvt(const float4* __restrict__ x, uint2* __restrict__ o) {
    int i = blockIdx.x * 256 + threadIdx.x;      // 1.6M total
    float4 v = x[i];
    uint2 r;
    r.x = bf_pack(v.x, v.y);
    r.y = bf_pack(v.z, v.w);
    o[i] = r;
}

// ---------------- W pre-pack into MFMA B-fragment order ----------------
__global__ __launch_bounds__(256) void k_packw(const float* __restrict__ Wn, const float* __restrict__ Wr,
                                               uint4* __restrict__ wp) {
    int idx = blockIdx.x * 256 + threadIdx.x;    // 12288 total
    int layer = idx >> 12;
    int rem = idx & 4095;
    int kb = rem >> 9;
    int n = (rem >> 2) & 127;
    int quad = rem & 3;
    float v[8];
#pragma unroll
    for (int j = 0; j < 8; j++) {
        int k = kb * 32 + quad * 8 + j;
        v[j] = (k < 128) ? Wn[layer * 16384 + k * 128 + n]
                         : Wr[layer * 16384 + (k - 128) * 128 + n];
    }
    uint4 r;
    r.x = bf_pack(v[0], v[1]);
    r.y = bf_pack(v[2], v[3]);
    r.z = bf_pack(v[4], v[5]);
    r.w = bf_pack(v[6], v[7]);
    wp[idx] = r;
}

// ---------------- CSR build: atomic-free (LDS histograms + block-partial scan) ----------------

__global__ __launch_bounds__(256) void k_hist(const int* __restrict__ ei, unsigned* __restrict__ hist) {
    __shared__ unsigned sh[NWORDS];
    for (int i = threadIdx.x; i < NWORDS; i += 256) sh[i] = 0;
    __syncthreads();
    const int e0 = blockIdx.x * EPB;
    for (int i = threadIdx.x; i < EPB; i += 256) {
        int d = __builtin_nontemporal_load(ei + N_EDGES + e0 + i);
        atomicAdd(&sh[d >> 1], 1u << ((d & 1) << 4));
    }
    __syncthreads();
    unsigned* hb = hist + (size_t)blockIdx.x * NWORDS;
    for (int i = threadIdx.x; i < NWORDS; i += 256) hb[i] = sh[i];
}

__global__ __launch_bounds__(256) void k_scanb(unsigned* __restrict__ hist, int* __restrict__ deg) {
    int w = blockIdx.x * 256 + threadIdx.x;
    if (w >= NWORDS) return;
    unsigned run = 0;
#pragma unroll 8
    for (int b = 0; b < HIST_BLOCKS; ++b) {
        unsigned u = hist[(size_t)b * NWORDS + w];
        hist[(size_t)b * NWORDS + w] = run;
        run += u;
    }
    deg[2 * w] = (int)(run & 0xffffu);
    deg[2 * w + 1] = (int)(run >> 16);
}

__global__ __launch_bounds__(256) void k_blockreduce(const int* __restrict__ deg, int* __restrict__ bsum) {
    __shared__ int s[256];
    int i = blockIdx.x * 256 + threadIdx.x;
    s[threadIdx.x] = (i < N_NODES) ? deg[i] : 0;
    __syncthreads();
    for (int d = 128; d > 0; d >>= 1) {
        if (threadIdx.x < d) s[threadIdx.x] += s[threadIdx.x + d];
        __syncthreads();
    }
    if (threadIdx.x == 0) bsum[blockIdx.x] = s[0];
}

__global__ __launch_bounds__(256) void k_scanblocks(const int* __restrict__ bsum, int* __restrict__ boff, int nb) {
    __shared__ int s[256];
    int t = threadIdx.x;
    int v = (t < nb) ? bsum[t] : 0;
    s[t] = v;
    __syncthreads();
    for (int d = 1; d < 256; d <<= 1) {
        int add = (t >= d) ? s[t - d] : 0;
        __syncthreads();
        s[t] += add;
        __syncthreads();
    }
    if (t < nb) boff[t] = s[t] - v;   // exclusive
}

__global__ __launch_bounds__(256) void k_offsets(const int* __restrict__ deg, const int* __restrict__ boff,
                                                 int* __restrict__ offs, float* __restrict__ invdeg) {
    __shared__ int s[256];
    int b = blockIdx.x, t = threadIdx.x;
    int i = b * 256 + t;
    int v = (i < N_NODES) ? deg[i] : 0;
    s[t] = v;
    __syncthreads();
    for (int d = 1; d < 256; d <<= 1) {
        int add = (t >= d) ? s[t - d] : 0;
        __syncthreads();
        s[t] += add;
        __syncthreads();
    }
    if (i < N_NODES) {
        offs[i] = boff[b] + s[t] - v;   // exclusive global offset
        invdeg[i] = 1.0f / fmaxf((float)v, 1.0f);
    }
}

// Stage 3: fill — all 4 node-range passes concurrent; LDS atomics only.
// csr stores PRE-SCALED src uint4-offsets (src*16).
__global__ __launch_bounds__(256) void k_fill2(const int* __restrict__ ei, const int* __restrict__ offs,
                                               const unsigned* __restrict__ hist, int* __restrict__ csr) {
    __shared__ unsigned scur[WPP];   // 25 KB
    const int s8 = blockIdx.x & 7;
    const int pass = s8 >> 1;                              // 0..3
    const int b = ((blockIdx.x >> 3) << 1) | (s8 & 1);     // 0..127 edge slice
    const int nbase = pass * NPP;
    const unsigned* hb = hist + (size_t)b * NWORDS + pass * WPP;
    for (int i = threadIdx.x; i < WPP; i += 256) scur[i] = hb[i];
    __syncthreads();
    const int e0 = b * EPB;
    for (int i = threadIdx.x; i < EPB; i += 256) {
        int d = __builtin_nontemporal_load(ei + N_EDGES + e0 + i);
        unsigned rd = (unsigned)(d - nbase);
        if (rd < (unsigned)NPP) {
            int s = ei[e0 + i];
            int sh = (rd & 1) << 4;
            unsigned old = atomicAdd(&scur[rd >> 1], 1u << sh);
            unsigned rel = (old >> sh) & 0xffffu;
            csr[offs[d] + (int)rel] = s * 16;   // pre-scaled uint4 row offset
        }
    }
}

// ---------------- fused layer: agg (gather) -> LDS -> MFMA GEMM -> LN -> ReLU ----------------
// Block: 32 nodes, 4 waves. Phase 1: wave w aggregates nodes w*8..w*8+7 (quarter-wave
// slots, 8-deep uint4 unroll = 8 loads in flight/lane); bf16 result to LDS A
// (row stride 17 uint4 -> 2-way-free banks). Phase 2: MFMA K=256 ([agg|x]@[Wn;Wr]):
// agg A-frags from LDS, x A-frags from global (block's own contiguous rows),
// B-frags pre-packed. Phase 3: bias+LN+ReLU, bf16 out (+fp32 node_emb on last layer).

__global__ __launch_bounds__(256) void k_layer(
        const uint4* __restrict__ xq, const int* __restrict__ csr,
        const int* __restrict__ offs, const int* __restrict__ deg,
        const float* __restrict__ invdeg, const uint4* __restrict__ wp,
        const float* __restrict__ bn, const float* __restrict__ gam,
        const float* __restrict__ bet, float* __restrict__ xout,
        unsigned* __restrict__ b16out, int write_f32) {
    __shared__ uint4 A[32 * 17];    // 8.5 KB agg fragments
    __shared__ float H[32 * 132];   // 16.9 KB LN round-trip

    const int t = threadIdx.x;
    const int wv = t >> 6;
    const int lane = t & 63;
    const int slot = lane >> 4;     // edge slot 0..3
    const int m = lane & 15;        // uint4 index within row
    const int row0 = blockIdx.x * 32;
    const uint4* xm = xq + m;

    // ---- phase 1: aggregate 8 nodes per wave ----
    for (int i = 0; i < 8; ++i) {
        int node = row0 + wv * 8 + i;
        if (node >= N_NODES) node = N_NODES - 1;
        node = __builtin_amdgcn_readfirstlane(node);
        const int beg = offs[node];
        const int dn = deg[node];
        float a0 = 0.f, a1 = 0.f, a2 = 0.f, a3 = 0.f, a4 = 0.f, a5 = 0.f, a6 = 0.f, a7 = 0.f;
        int j = slot;
        for (; j + 32 <= dn; j += 32) {     // 8 gathers in flight
            int s0 = csr[beg + j];
            int s1 = csr[beg + j + 4];
            int s2 = csr[beg + j + 8];
            int s3 = csr[beg + j + 12];
            int s4 = csr[beg + j + 16];
            int s5 = csr[beg + j + 20];
            int s6 = csr[beg + j + 24];
            int s7 = csr[beg + j + 28];
            uint4 u0 = xm[s0], u1 = xm[s1], u2 = xm[s2], u3 = xm[s3];
            uint4 u4 = xm[s4], u5 = xm[s5], u6 = xm[s6], u7 = xm[s7];
            a0 += ((bf_lo(u0.x) + bf_lo(u1.x)) + (bf_lo(u2.x) + bf_lo(u3.x))) + ((bf_lo(u4.x) + bf_lo(u5.x)) + (bf_lo(u6.x) + bf_lo(u7.x)));
            a1 += ((bf_hi(u0.x) + bf_hi(u1.x)) + (bf_hi(u2.x) + bf_hi(u3.x))) + ((bf_hi(u4.x) + bf_hi(u5.x)) + (bf_hi(u6.x) + bf_hi(u7.x)));
            a2 += ((bf_lo(u0.y) + bf_lo(u1.y)) + (bf_lo(u2.y) + bf_lo(u3.y))) + ((bf_lo(u4.y) + bf_lo(u5.y)) + (bf_lo(u6.y) + bf_lo(u7.y)));
            a3 += ((bf_hi(u0.y) + bf_hi(u1.y)) + (bf_hi(u2.y) + bf_hi(u3.y))) + ((bf_hi(u4.y) + bf_hi(u5.y)) + (bf_hi(u6.y) + bf_hi(u7.y)));
            a4 += ((bf_lo(u0.z) + bf_lo(u1.z)) + (bf_lo(u2.z) + bf_lo(u3.z))) + ((bf_lo(u4.z) + bf_lo(u5.z)) + (bf_lo(u6.z) + bf_lo(u7.z)));
            a5 += ((bf_hi(u0.z) + bf_hi(u1.z)) + (bf_hi(u2.z) + bf_hi(u3.z))) + ((bf_hi(u4.z) + bf_hi(u5.z)) + (bf_hi(u6.z) + bf_hi(u7.z)));
            a6 += ((bf_lo(u0.w) + bf_lo(u1.w)) + (bf_lo(u2.w) + bf_lo(u3.w))) + ((bf_lo(u4.w) + bf_lo(u5.w)) + (bf_lo(u6.w) + bf_lo(u7.w)));
            a7 += ((bf_hi(u0.w) + bf_hi(u1.w)) + (bf_hi(u2.w) + bf_hi(u3.w))) + ((bf_hi(u4.w) + bf_hi(u5.w)) + (bf_hi(u6.w) + bf_hi(u7.w)));
        }
        for (; j + 16 <= dn; j += 16) {
            int s0 = csr[beg + j];
            int s1 = csr[beg + j + 4];
            int s2 = csr[beg + j + 8];
            int s3 = csr[beg + j + 12];
            uint4 u0 = xm[s0], u1 = xm[s1], u2 = xm[s2], u3 = xm[s3];
            a0 += (bf_lo(u0.x) + bf_lo(u1.x)) + (bf_lo(u2.x) + bf_lo(u3.x));
            a1 += (bf_hi(u0.x) + bf_hi(u1.x)) + (bf_hi(u2.x) + bf_hi(u3.x));
            a2 += (bf_lo(u0.y) + bf_lo(u1.y)) + (bf_lo(u2.y) + bf_lo(u3.y));
            a3 += (bf_hi(u0.y) + bf_hi(u1.y)) + (bf_hi(u2.y) + bf_hi(u3.y));
            a4 += (bf_lo(u0.z) + bf_lo(u1.z)) + (bf_lo(u2.z) + bf_lo(u3.z));
            a5 += (bf_hi(u0.z) + bf_hi(u1.z)) + (bf_hi(u2.z) + bf_hi(u3.z));
            a6 += (bf_lo(u0.w) + bf_lo(u1.w)) + (bf_lo(u2.w) + bf_lo(u3.w));
            a7 += (bf_hi(u0.w) + bf_hi(u1.w)) + (bf_hi(u2.w) + bf_hi(u3.w));
        }
        for (; j < dn; j += 4) {
            uint4 u0 = xm[csr[beg + j]];
            a0 += bf_lo(u0.x); a1 += bf_hi(u0.x);
            a2 += bf_lo(u0.y); a3 += bf_hi(u0.y);
            a4 += bf_lo(u0.z); a5 += bf_hi(u0.z);
            a6 += bf_lo(u0.w); a7 += bf_hi(u0.w);
        }
#pragma unroll
        for (int msk = 16; msk < 64; msk <<= 1) {
            a0 += __shfl_xor(a0, msk); a1 += __shfl_xor(a1, msk);
            a2 += __shfl_xor(a2, msk); a3 += __shfl_xor(a3, msk);
            a4 += __shfl_xor(a4, msk); a5 += __shfl_xor(a5, msk);
            a6 += __shfl_xor(a6, msk); a7 += __shfl_xor(a7, msk);
        }
        if (slot == 0) {
            float id = invdeg[node];
            uint4 r;
            r.x = bf_pack(a0 * id, a1 * id);
            r.y = bf_pack(a2 * id, a3 * id);
            r.z = bf_pack(a4 * id, a5 * id);
            r.w = bf_pack(a6 * id, a7 * id);
            A[(wv * 8 + i) * 17 + m] = r;
        }
    }
    __syncthreads();

    // ---- phase 2: MFMA GEMM (K=256) ----
    const int quad = lane >> 4;
    const int nl = lane & 15;
    const int nb = wv * 32;
    int r0 = row0 + nl;
    int r1 = row0 + 16 + nl;
    if (r0 >= N_NODES) r0 = N_NODES - 1;
    if (r1 >= N_NODES) r1 = N_NODES - 1;

    floatx4 acc00 = {0.f, 0.f, 0.f, 0.f}, acc01 = acc00, acc10 = acc00, acc11 = acc00;
#pragma unroll
    for (int kb = 0; kb < 8; ++kb) {
        uint4 a0, a1;
        if (kb < 4) {
            a0 = A[nl * 17 + kb * 4 + quad];
            a1 = A[(16 + nl) * 17 + kb * 4 + quad];
        } else {
            const int kk = kb & 3;
            a0 = xq[r0 * 16 + kk * 4 + quad];
            a1 = xq[r1 * 16 + kk * 4 + quad];
        }
        uint4 b0 = wp[(kb * 128 + nb + nl) * 4 + quad];
        uint4 b1 = wp[(kb * 128 + nb + 16 + nl) * 4 + quad];
        short8 a0s = *(short8*)&a0, a1s = *(short8*)&a1;
        short8 b0s = *(short8*)&b0, b1s = *(short8*)&b1;
        acc00 = __builtin_amdgcn_mfma_f32_16x16x32_bf16(a0s, b0s, acc00, 0, 0, 0);
        acc01 = __builtin_amdgcn_mfma_f32_16x16x32_bf16(a0s, b1s, acc01, 0, 0, 0);
        acc10 = __builtin_amdgcn_mfma_f32_16x16x32_bf16(a1s, b0s, acc10, 0, 0, 0);
        acc11 = __builtin_amdgcn_mfma_f32_16x16x32_bf16(a1s, b1s, acc11, 0, 0, 0);
    }

    // ---- phase 3: bias -> H -> LayerNorm -> ReLU -> store ----
    float bn0 = bn[nb + nl];
    float bn1 = bn[nb + 16 + nl];
#pragma unroll
    for (int reg = 0; reg < 4; ++reg) {
        int rr = quad * 4 + reg;
        H[rr * 132 + nb + nl] = acc00[reg] + bn0;
        H[rr * 132 + nb + 16 + nl] = acc01[reg] + bn1;
        H[(16 + rr) * 132 + nb + nl] = acc10[reg] + bn0;
        H[(16 + rr) * 132 + nb + 16 + nl] = acc11[reg] + bn1;
    }
    __syncthreads();

    int row = t >> 3;    // 0..31
    int sub = t & 7;
    const float* hr = &H[row * 132 + sub * 16];
    float v[16];
    float s = 0.f, s2 = 0.f;
#pragma unroll
    for (int i = 0; i < 16; i++) {
        v[i] = hr[i];
        s += v[i];
        s2 += v[i] * v[i];
    }
#pragma unroll
    for (int msk = 1; msk < 8; msk <<= 1) {
        s += __shfl_xor(s, msk);
        s2 += __shfl_xor(s2, msk);
    }
    float mean = s * (1.f / 128.f);
    float var = s2 * (1.f / 128.f) - mean * mean;
    float rstd = rsqrtf(var + 1e-5f);
    int gr = row0 + row;
    if (gr < N_NODES) {
        int cb = sub * 16;
        float o[16];
#pragma unroll
        for (int i = 0; i < 16; i++) {
            int c = cb + i;
            o[i] = fmaxf((v[i] - mean) * rstd * gam[c] + bet[c], 0.f);
        }
        if (write_f32) {
#pragma unroll
            for (int i = 0; i < 16; i += 4)
                *(float4*)&xout[(size_t)gr * HID + cb + i] = *(float4*)&o[i];
        }
        unsigned p[8];
#pragma unroll
        for (int i = 0; i < 8; i++) p[i] = bf_pack(o[2 * i], o[2 * i + 1]);
        *(uint4*)&b16out[(size_t)gr * 64 + (cb >> 1)] = *(uint4*)&p[0];
        *(uint4*)&b16out[(size_t)gr * 64 + (cb >> 1) + 4] = *(uint4*)&p[4];
    }
}

// ---------------- graph mean-pool: segmented reduction, 1024 threads (16 rows in flight) ----------------

__global__ __launch_bounds__(1024) void k_pool_seg(const unsigned* __restrict__ xb,
                                                   const int* __restrict__ batch,
                                                   float* __restrict__ out) {
    const int g = blockIdx.x;          // 0..63
    __shared__ int s_beg, s_end;
    if (threadIdx.x == 0) {
        int lo = 0, hi = N_NODES;
        while (lo < hi) { int mid = (lo + hi) >> 1; if (batch[mid] < g) lo = mid + 1; else hi = mid; }
        s_beg = lo;
        lo = 0; hi = N_NODES;
        while (lo < hi) { int mid = (lo + hi) >> 1; if (batch[mid] < g + 1) lo = mid + 1; else hi = mid; }
        s_end = lo;
    }
    __syncthreads();
    const int beg = s_beg, end = s_end;
    const int w = threadIdx.x & 63;    // u32 word (2 cols)
    const int q = threadIdx.x >> 6;    // row group 0..15
    float ax = 0.f, ay = 0.f;
    for (int r = beg + q; r < end; r += 16) {
        unsigned u = xb[(size_t)r * 64 + w];
        ax += bf_lo(u);
        ay += bf_hi(u);
    }
    __shared__ float sx[16][64], sy[16][64];
    sx[q][w] = ax;
    sy[q][w] = ay;
    __syncthreads();
    if (q == 0) {
        float tx = 0.f, ty = 0.f;
#pragma unroll
        for (int i = 0; i < 16; i++) { tx += sx[i][w]; ty += sy[i][w]; }
        float inv = 1.f / fmaxf((float)(end - beg), 1.f);
        float2 r;
        r.x = tx * inv;
        r.y = ty * inv;
        *(float2*)&out[(g << 7) + w * 2] = r;
    }
}

extern "C" void kernel_launch(void* const* d_in, const int* in_sizes, int n_in,
                              void* d_out, int out_size, void* d_ws, size_t ws_size,
                              hipStream_t stream) {
    const float* x0 = (const float*)d_in[0];
    const float* Wn = (const float*)d_in[1];
    const float* bn = (const float*)d_in[2];
    const float* Wr = (const float*)d_in[3];
    const float* gam = (const float*)d_in[4];
    const float* bet = (const float*)d_in[5];
    const int* ei = (const int*)d_in[6];
    const int* batch = (const int*)d_in[7];

    float* out = (float*)d_out;                 // [0,8192): graph_emb ; [8192,...): node_emb
    float* node_out = out + N_GRAPHS * HID;

    unsigned* ws = (unsigned*)d_ws;
    int* deg = (int*)(ws + WS_DEG);
    int* bsum = (int*)(ws + WS_BSUM);
    int* boff = (int*)(ws + WS_BOFF);
    int* offs = (int*)(ws + WS_OFFS);
    float* invdeg = (float*)(ws + WS_INVD);
    int* csr = (int*)(ws + WS_CSR);
    unsigned* hist = ws + WS_XB_B;    // hist during build; x buffer B after
    unsigned* xa = ws + WS_XB_A;      // x buffer A
    unsigned* xbb = ws + WS_XB_B;
    uint4* wp = (uint4*)(ws + WS_WP);

    const int nb = (N_NODES + 255) / 256;          // 196
    k_cvt<<<(N_NODES * HID / 4) / 256, 256, 0, stream>>>((const float4*)x0, (uint2*)xa);
    k_packw<<<48, 256, 0, stream>>>(Wn, Wr, wp);
    k_hist<<<HIST_BLOCKS, 256, 0, stream>>>(ei, hist);
    k_scanb<<<(NWORDS + 255) / 256, 256, 0, stream>>>(hist, deg);
    k_blockreduce<<<nb, 256, 0, stream>>>(deg, bsum);
    k_scanblocks<<<1, 256, 0, stream>>>(bsum, boff, nb);
    k_offsets<<<nb, 256, 0, stream>>>(deg, boff, offs, invdeg);
    k_fill2<<<HIST_BLOCKS * FILL_PASSES, 256, 0, stream>>>(ei, offs, hist, csr);

    const int gb = (N_NODES + 31) / 32;            // 1563

    // ping-pong: l0 A->B, l1 B->A, l2 A->B (fused layer cannot run in-place)
    for (int l = 0; l < 3; ++l) {
        const unsigned* xin = (l & 1) ? xbb : xa;
        unsigned* xout16 = (l & 1) ? xa : xbb;
        k_layer<<<gb, 256, 0, stream>>>((const uint4*)xin, csr, offs, deg, invdeg,
                                        wp + (size_t)l * 4096, bn + (size_t)l * HID,
                                        gam + (size_t)l * HID, bet + (size_t)l * HID,
                                        node_out, xout16, l == 2 ? 1 : 0);
    }

    k_pool_seg<<<N_GRAPHS, 1024, 0, stream>>>(xbb, batch, out);
}